// Round 14
// baseline (3415.247 us; speedup 1.0000x reference)
//
#include <hip/hip_runtime.h>
#include <math.h>

#define NB 16
#define PP 1024
#define DD 64
#define MAX_ITER 10
#define CH (NB * PP)           // partial-chunk stride (16384)
#define WPB 64                 // workgroups per batch

constexpr float EPSV    = 0.1f;
constexpr float SCALE_G = 20.0f;     // 2/eps
constexpr float LOG2E   = 1.44269504088896340736f;
constexpr float LOG_MU  = -6.93146156597137f;   // log(1/1024 + 1e-8)
constexpr float THRESHV = 0.1f;

typedef short bf16x8 __attribute__((ext_vector_type(8)));
typedef float f32x16 __attribute__((ext_vector_type(16)));

__device__ __forceinline__ unsigned short f2bf(float f) {
  unsigned int u = __float_as_uint(f);
  return (unsigned short)((u + 0x7FFFu + ((u >> 16) & 1u)) >> 16);   // RNE
}
__device__ __forceinline__ float bf2f(unsigned short h) {
  return __uint_as_float(((unsigned int)h) << 16);
}

// Packed-fragment addressing (validated r13): pk[((g*4+q)*64+lane)*8] = the
// bf16x8 lane needs for K-slice q of 32-row group g. Same layout for A and B.
__device__ __forceinline__ const bf16x8* frag(const unsigned short* pk, int g, int q, int l) {
  return (const bf16x8*)(pk + (((size_t)g * 4 + q) * 64 + l) * 8);
}

// Monotonic-target barriers (no counter reset -> no reset races).
__device__ __forceinline__ void batch_barrier(int* cnt, int target) {
  __syncthreads();
  if (threadIdx.x == 0) {
    __threadfence();
    atomicAdd(cnt, 1);
    while (__hip_atomic_load(cnt, __ATOMIC_ACQUIRE, __HIP_MEMORY_SCOPE_AGENT) < target)
      __builtin_amdgcn_s_sleep(2);
    __threadfence();
  }
  __syncthreads();
}
__device__ __forceinline__ void grid_barrier2(int* bcnt, int* root, int isLeader,
                                              int btarget, int rtarget) {
  __syncthreads();
  if (threadIdx.x == 0) {
    __threadfence();
    atomicAdd(bcnt, 1);
    if (isLeader) {
      while (__hip_atomic_load(bcnt, __ATOMIC_ACQUIRE, __HIP_MEMORY_SCOPE_AGENT) < btarget)
        __builtin_amdgcn_s_sleep(2);
      atomicAdd(root, 1);
    }
    while (__hip_atomic_load(root, __ATOMIC_ACQUIRE, __HIP_MEMORY_SCOPE_AGENT) < rtarget)
      __builtin_amdgcn_s_sleep(2);
    __threadfence();
  }
  __syncthreads();
}

// ---------------------------------------------------------------------------
// Prep (validated r13): bf16 hi/lo split into packed fragments + norms.
// Block 0 additionally zeroes the barrier counters (fresh every call).
// ---------------------------------------------------------------------------
__global__ __launch_bounds__(256) void prep_kernel(
    const float* __restrict__ x, const float* __restrict__ y,
    unsigned short* __restrict__ xhp, unsigned short* __restrict__ xlp,
    unsigned short* __restrict__ yhp, unsigned short* __restrict__ ylp,
    float* __restrict__ nxs, float* __restrict__ nys, int* __restrict__ bars)
{
  if (blockIdx.x == 0 && threadIdx.x < 33) bars[threadIdx.x] = 0;

  const int sel = blockIdx.x >> 9;
  const int row = (blockIdx.x & 511) * 32 + (threadIdx.x >> 3);
  const int q   = threadIdx.x & 7;

  const float* src = sel ? y : x;
  unsigned short* H = sel ? yhp : xhp;
  unsigned short* L = sel ? ylp : xlp;
  float* N          = sel ? nys : nxs;

  const float* p = src + (size_t)row * DD + q * 8;
  float4 v0 = *(const float4*)(p);
  float4 v1 = *(const float4*)(p + 4);

  float f[8] = {v0.x, v0.y, v0.z, v0.w, v1.x, v1.y, v1.z, v1.w};
  float nrm = 0.f;
  unsigned short hb[8], lb[8];
  #pragma unroll
  for (int k = 0; k < 8; ++k) {
    nrm = fmaf(f[k], f[k], nrm);
    unsigned short h = f2bf(f[k]);
    float res = f[k] - bf2f(h);
    hb[k] = h; lb[k] = f2bf(res);
  }
  nrm += __shfl_xor(nrm, 1);
  nrm += __shfl_xor(nrm, 2);
  nrm += __shfl_xor(nrm, 4);
  if (q == 0) N[row] = 10.0f * nrm;

  uint4 ho, lo;
  ho.x = hb[0] | ((unsigned)hb[1] << 16); ho.y = hb[2] | ((unsigned)hb[3] << 16);
  ho.z = hb[4] | ((unsigned)hb[5] << 16); ho.w = hb[6] | ((unsigned)hb[7] << 16);
  lo.x = lb[0] | ((unsigned)lb[1] << 16); lo.y = lb[2] | ((unsigned)lb[3] << 16);
  lo.z = lb[4] | ((unsigned)lb[5] << 16); lo.w = lb[6] | ((unsigned)lb[7] << 16);

  const int grp  = row >> 5;
  const int lane = (row & 31) + 32 * (q & 1);
  const size_t dst = (((size_t)grp * 4 + (q >> 1)) * 64 + lane) * 8;
  *(uint4*)(H + dst) = ho;
  *(uint4*)(L + dst) = lo;
}

// ---------------------------------------------------------------------------
// The whole 10-iteration Sinkhorn loop in ONE dispatch. Grid 1024 x 256,
// __launch_bounds__(256,4): grid == 4 blocks/CU x 256 CUs (co-resident by
// capacity; guide §1 pattern). Block = (n = bid&15, rem = bid>>4).
// Phase bodies are the validated r13 u_half / v_half verbatim.
// ---------------------------------------------------------------------------
__global__ __launch_bounds__(256, 4) void sinkhorn_iterate(
    const unsigned short* __restrict__ xhp, const unsigned short* __restrict__ xlp,
    const unsigned short* __restrict__ yhp, const unsigned short* __restrict__ ylp,
    const float* __restrict__ nxs, const float* __restrict__ nys,
    float* __restrict__ pmU, float* __restrict__ psU,
    float* __restrict__ pmV, float* __restrict__ psV,
    float* __restrict__ atPrev, float* __restrict__ errD,
    int* __restrict__ barU, int* __restrict__ barV, int* __restrict__ root)
{
  const int tid = threadIdx.x;
  const int n     = blockIdx.x & 15;
  const int rem   = blockIdx.x >> 4;
  const int otile = rem >> 1;
  const int rc    = rem & 1;
  const int l     = tid & 63;
  const int w     = tid >> 6;

  __shared__ float bias[PP];
  __shared__ float mred[4][32];
  __shared__ float sred[4][32];
  __shared__ float red4[4];

  const int gB = n * 32 + otile;

  for (int it = 0; it < MAX_ITER; ++it) {
    int done = 0;
    if (it > 0) {
      float tot = 0.f;
      #pragma unroll
      for (int k = 0; k < NB; ++k) tot += ((const volatile float*)errD)[k];
      done = (tot * (EPSV / (float)NB) < THRESHV) ? 1 : 0;
    }

    // ================= U phase (A=y reduce, B=x out) =================
    if (!done) {
      {
        const int e0 = tid * 4;
        if (it == 0) {
          float4 nv = *(const float4*)(nys + n * PP + e0);
          bias[e0+0] = -nv.x; bias[e0+1] = -nv.y; bias[e0+2] = -nv.z; bias[e0+3] = -nv.w;
        } else {
          float4 m0 = *(const float4*)(pmV + 0 * CH + n * PP + e0);
          float4 m1 = *(const float4*)(pmV + 1 * CH + n * PP + e0);
          float4 s0 = *(const float4*)(psV + 0 * CH + n * PP + e0);
          float4 s1 = *(const float4*)(psV + 1 * CH + n * PP + e0);
          float mm, ss;
          mm = fmaxf(m0.x, m1.x);
          ss = s0.x * exp2f((m0.x - mm) * LOG2E) + s1.x * exp2f((m1.x - mm) * LOG2E);
          bias[e0+0] = LOG_MU - (mm + logf(ss));
          mm = fmaxf(m0.y, m1.y);
          ss = s0.y * exp2f((m0.y - mm) * LOG2E) + s1.y * exp2f((m1.y - mm) * LOG2E);
          bias[e0+1] = LOG_MU - (mm + logf(ss));
          mm = fmaxf(m0.z, m1.z);
          ss = s0.z * exp2f((m0.z - mm) * LOG2E) + s1.z * exp2f((m1.z - mm) * LOG2E);
          bias[e0+2] = LOG_MU - (mm + logf(ss));
          mm = fmaxf(m0.w, m1.w);
          ss = s0.w * exp2f((m0.w - mm) * LOG2E) + s1.w * exp2f((m1.w - mm) * LOG2E);
          bias[e0+3] = LOG_MU - (mm + logf(ss));
        }
      }
      __syncthreads();

      bf16x8 Bh[4], Bl[4];
      #pragma unroll
      for (int q = 0; q < 4; ++q) {
        Bh[q] = *frag(xhp, gB, q, l);
        Bl[q] = *frag(xlp, gB, q, l);
      }

      float M = -INFINITY;
      #pragma unroll
      for (int jt = 0; jt < 4; ++jt) {
        const int gl = rc * 16 + w * 4 + jt;
        const int gA = n * 32 + gl;
        f32x16 a0;
        #pragma unroll
        for (int z = 0; z < 16; ++z) a0[z] = 0.f;
        #pragma unroll
        for (int q = 0; q < 4; ++q)
          a0 = __builtin_amdgcn_mfma_f32_32x32x16_bf16(*frag(yhp, gA, q, l), Bh[q], a0, 0, 0, 0);
        const int jb = gl * 32 + 4 * (l >> 5);
        #pragma unroll
        for (int r = 0; r < 16; ++r)
          M = fmaxf(M, fmaf(SCALE_G, a0[r], bias[jb + (r & 3) + 8 * (r >> 2)]));
      }
      M = fmaxf(M, __shfl_xor(M, 32));
      if (l < 32) mred[w][l] = M;
      __syncthreads();
      const int c = l & 31;
      const float Mf = fmaxf(fmaxf(mred[0][c], mred[1][c]), fmaxf(mred[2][c], mred[3][c]));

      float S = 0.f;
      #pragma unroll
      for (int jt = 0; jt < 4; ++jt) {
        const int gl = rc * 16 + w * 4 + jt;
        const int gA = n * 32 + gl;
        f32x16 a0, a1, a2;
        #pragma unroll
        for (int z = 0; z < 16; ++z) { a0[z] = 0.f; a1[z] = 0.f; a2[z] = 0.f; }
        #pragma unroll
        for (int q = 0; q < 4; ++q) {
          bf16x8 Ah = *frag(yhp, gA, q, l);
          bf16x8 Al = *frag(ylp, gA, q, l);
          a0 = __builtin_amdgcn_mfma_f32_32x32x16_bf16(Ah, Bh[q], a0, 0, 0, 0);
          a1 = __builtin_amdgcn_mfma_f32_32x32x16_bf16(Ah, Bl[q], a1, 0, 0, 0);
          a2 = __builtin_amdgcn_mfma_f32_32x32x16_bf16(Al, Bh[q], a2, 0, 0, 0);
        }
        const int jb = gl * 32 + 4 * (l >> 5);
        #pragma unroll
        for (int r = 0; r < 16; ++r)
          S += exp2f((fmaf(SCALE_G, a0[r] + a1[r] + a2[r], bias[jb + (r & 3) + 8 * (r >> 2)]) - Mf) * LOG2E);
      }
      S += __shfl_xor(S, 32);
      if (l < 32) sred[w][l] = S;
      __syncthreads();

      if (tid < 32) {
        float Sf = sred[0][tid] + sred[1][tid] + sred[2][tid] + sred[3][tid];
        float Mc = fmaxf(fmaxf(mred[0][tid], mred[1][tid]), fmaxf(mred[2][tid], mred[3][tid]));
        const int gi = n * PP + otile * 32 + tid;
        pmU[rc * CH + gi] = Mc;
        psU[rc * CH + gi] = Sf;
      }
    }

    batch_barrier(&barU[n], WPB * (it + 1));

    // ================= V phase (A=x reduce, B=y out) =================
    if (!done) {
      float dsumT = 0.f;
      {
        const int e0 = tid * 4;
        float4 m0 = *(const float4*)(pmU + 0 * CH + n * PP + e0);
        float4 m1 = *(const float4*)(pmU + 1 * CH + n * PP + e0);
        float4 s0 = *(const float4*)(psU + 0 * CH + n * PP + e0);
        float4 s1 = *(const float4*)(psU + 1 * CH + n * PP + e0);
        float at4[4];
        float mm, ss;
        mm = fmaxf(m0.x, m1.x);
        ss = s0.x * exp2f((m0.x - mm) * LOG2E) + s1.x * exp2f((m1.x - mm) * LOG2E);
        at4[0] = LOG_MU - (mm + logf(ss));
        mm = fmaxf(m0.y, m1.y);
        ss = s0.y * exp2f((m0.y - mm) * LOG2E) + s1.y * exp2f((m1.y - mm) * LOG2E);
        at4[1] = LOG_MU - (mm + logf(ss));
        mm = fmaxf(m0.z, m1.z);
        ss = s0.z * exp2f((m0.z - mm) * LOG2E) + s1.z * exp2f((m1.z - mm) * LOG2E);
        at4[2] = LOG_MU - (mm + logf(ss));
        mm = fmaxf(m0.w, m1.w);
        ss = s0.w * exp2f((m0.w - mm) * LOG2E) + s1.w * exp2f((m1.w - mm) * LOG2E);
        at4[3] = LOG_MU - (mm + logf(ss));
        bias[e0+0] = at4[0]; bias[e0+1] = at4[1]; bias[e0+2] = at4[2]; bias[e0+3] = at4[3];
        if (rem == 0) {
          if (it == 0) {
            float4 nx = *(const float4*)(nxs + n * PP + e0);
            dsumT = fabsf(at4[0] + nx.x) + fabsf(at4[1] + nx.y)
                  + fabsf(at4[2] + nx.z) + fabsf(at4[3] + nx.w);
          } else {
            float4 ap = *(const float4*)(atPrev + n * PP + e0);
            dsumT = fabsf(at4[0] - ap.x) + fabsf(at4[1] - ap.y)
                  + fabsf(at4[2] - ap.z) + fabsf(at4[3] - ap.w);
          }
          *(float4*)(atPrev + n * PP + e0) = make_float4(at4[0], at4[1], at4[2], at4[3]);
        }
      }
      __syncthreads();

      bf16x8 Bh[4], Bl[4];
      #pragma unroll
      for (int q = 0; q < 4; ++q) {
        Bh[q] = *frag(yhp, gB, q, l);
        Bl[q] = *frag(ylp, gB, q, l);
      }

      float M = -INFINITY;
      #pragma unroll
      for (int jt = 0; jt < 4; ++jt) {
        const int gl = rc * 16 + w * 4 + jt;
        const int gA = n * 32 + gl;
        f32x16 a0;
        #pragma unroll
        for (int z = 0; z < 16; ++z) a0[z] = 0.f;
        #pragma unroll
        for (int q = 0; q < 4; ++q)
          a0 = __builtin_amdgcn_mfma_f32_32x32x16_bf16(*frag(xhp, gA, q, l), Bh[q], a0, 0, 0, 0);
        const int jb = gl * 32 + 4 * (l >> 5);
        #pragma unroll
        for (int r = 0; r < 16; ++r)
          M = fmaxf(M, fmaf(SCALE_G, a0[r], bias[jb + (r & 3) + 8 * (r >> 2)]));
      }
      M = fmaxf(M, __shfl_xor(M, 32));
      if (l < 32) mred[w][l] = M;
      __syncthreads();
      const int c = l & 31;
      const float Mf = fmaxf(fmaxf(mred[0][c], mred[1][c]), fmaxf(mred[2][c], mred[3][c]));

      float S = 0.f;
      #pragma unroll
      for (int jt = 0; jt < 4; ++jt) {
        const int gl = rc * 16 + w * 4 + jt;
        const int gA = n * 32 + gl;
        f32x16 a0, a1, a2;
        #pragma unroll
        for (int z = 0; z < 16; ++z) { a0[z] = 0.f; a1[z] = 0.f; a2[z] = 0.f; }
        #pragma unroll
        for (int q = 0; q < 4; ++q) {
          bf16x8 Ah = *frag(xhp, gA, q, l);
          bf16x8 Al = *frag(xlp, gA, q, l);
          a0 = __builtin_amdgcn_mfma_f32_32x32x16_bf16(Ah, Bh[q], a0, 0, 0, 0);
          a1 = __builtin_amdgcn_mfma_f32_32x32x16_bf16(Ah, Bl[q], a1, 0, 0, 0);
          a2 = __builtin_amdgcn_mfma_f32_32x32x16_bf16(Al, Bh[q], a2, 0, 0, 0);
        }
        const int jb = gl * 32 + 4 * (l >> 5);
        #pragma unroll
        for (int r = 0; r < 16; ++r)
          S += exp2f((fmaf(SCALE_G, a0[r] + a1[r] + a2[r], bias[jb + (r & 3) + 8 * (r >> 2)]) - Mf) * LOG2E);
      }
      S += __shfl_xor(S, 32);
      if (l < 32) sred[w][l] = S;
      __syncthreads();

      if (tid < 32) {
        float Sf = sred[0][tid] + sred[1][tid] + sred[2][tid] + sred[3][tid];
        float Mc = fmaxf(fmaxf(mred[0][tid], mred[1][tid]), fmaxf(mred[2][tid], mred[3][tid]));
        const int gi = n * PP + otile * 32 + tid;
        pmV[rc * CH + gi] = Mc;
        psV[rc * CH + gi] = Sf;
      }

      if (rem == 0) {
        #pragma unroll
        for (int off = 32; off; off >>= 1) dsumT += __shfl_xor(dsumT, off);
        if (l == 0) red4[w] = dsumT;
      }
      __syncthreads();
      if (rem == 0 && tid == 0)
        errD[n] = red4[0] + red4[1] + red4[2] + red4[3];
    }
    // frozen: errD untouched (stays below threshold) — matches reference freeze

    grid_barrier2(&barV[n], root, (rem == 0) ? 1 : 0, WPB * (it + 1), NB * (it + 1));
  }
}

// ---------------------------------------------------------------------------
// atF_i = LOG_MU - lse_U(i) = a_i - nxs_i ; btF_j = LOG_MU - lse_V(j).
// ---------------------------------------------------------------------------
__global__ __launch_bounds__(256) void finalize_duals(
    const float* __restrict__ pmU, const float* __restrict__ psU,
    const float* __restrict__ pmV, const float* __restrict__ psV,
    float* __restrict__ atF, float* __restrict__ btF)
{
  const int gi = blockIdx.x * 256 + threadIdx.x;
  float m0 = pmU[gi], m1 = pmU[CH + gi];
  float s0 = psU[gi], s1 = psU[CH + gi];
  float mm = fmaxf(m0, m1);
  float ss = s0 * exp2f((m0 - mm) * LOG2E) + s1 * exp2f((m1 - mm) * LOG2E);
  atF[gi] = LOG_MU - (mm + logf(ss));
  m0 = pmV[gi]; m1 = pmV[CH + gi];
  s0 = psV[gi]; s1 = psV[CH + gi];
  mm = fmaxf(m0, m1);
  ss = s0 * exp2f((m0 - mm) * LOG2E) + s1 * exp2f((m1 - mm) * LOG2E);
  btF[gi] = LOG_MU - (mm + logf(ss));
}

// ---------------------------------------------------------------------------
// pi_ij = exp(atF_i + btF_j + 20*<x_i,y_j>) — validated compute_c_mfma body
// with the exp-write fused in (identical index math; saves a 128 MB pass).
// ---------------------------------------------------------------------------
__global__ __launch_bounds__(256) void pi_mfma(
    const unsigned short* __restrict__ xhp, const unsigned short* __restrict__ xlp,
    const unsigned short* __restrict__ yhp, const unsigned short* __restrict__ ylp,
    const float* __restrict__ atF, const float* __restrict__ btF,
    float* __restrict__ pi)
{
  const int n   = blockIdx.x & 15;
  const int ib  = (blockIdx.x >> 4) & 15;
  const int jb  = blockIdx.x >> 8;
  const int tid = threadIdx.x;
  const int l   = tid & 63;
  const int w   = tid >> 6;
  const int ih  = w & 1, jh = w >> 1;

  __shared__ float atv[64];
  if (tid < 64) atv[tid] = atF[n * PP + ib * 64 + tid];
  __syncthreads();

  const int jg  = n * PP + jb * 64 + 32 * jh + (l & 31);
  const float btv = btF[jg];

  const int gX = n * 32 + ib * 2 + ih;
  const int gY = n * 32 + jb * 2 + jh;

  f32x16 acc;
  #pragma unroll
  for (int z = 0; z < 16; ++z) acc[z] = 0.f;
  #pragma unroll
  for (int q = 0; q < 4; ++q) {
    bf16x8 Xh = *frag(xhp, gX, q, l);
    bf16x8 Xl = *frag(xlp, gX, q, l);
    bf16x8 Yh = *frag(yhp, gY, q, l);
    bf16x8 Yl = *frag(ylp, gY, q, l);
    acc = __builtin_amdgcn_mfma_f32_32x32x16_bf16(Xh, Yh, acc, 0, 0, 0);
    acc = __builtin_amdgcn_mfma_f32_32x32x16_bf16(Xh, Yl, acc, 0, 0, 0);
    acc = __builtin_amdgcn_mfma_f32_32x32x16_bf16(Xl, Yh, acc, 0, 0, 0);
  }

  const int irb  = 32 * ih + 4 * (l >> 5);
  const int jcol = jb * 64 + 32 * jh + (l & 31);
  #pragma unroll
  for (int r = 0; r < 16; ++r) {
    const int irel = irb + (r & 3) + 8 * (r >> 2);
    const size_t off = ((size_t)(n * PP + ib * 64 + irel)) * PP + jcol;
    pi[off] = exp2f((atv[irel] + btv + SCALE_G * acc[r]) * LOG2E);
  }
}

extern "C" void kernel_launch(void* const* d_in, const int* in_sizes, int n_in,
                              void* d_out, int out_size, void* d_ws, size_t ws_size,
                              hipStream_t stream)
{
  const float* y = (const float*)d_in[0];   // setup_inputs order: y first
  const float* x = (const float*)d_in[1];
  float* pi = (float*)d_out;

  const size_t NE = (size_t)NB * PP * DD;
  unsigned short* xhp = (unsigned short*)d_ws;
  unsigned short* xlp = xhp + NE;
  unsigned short* yhp = xlp + NE;
  unsigned short* ylp = yhp + NE;
  float* nxs    = (float*)(ylp + NE);        // CH floats
  float* nys    = nxs + CH;                  // CH
  float* pmU    = nys + CH;                  // 2*CH
  float* psU    = pmU + 2 * CH;
  float* pmV    = psU + 2 * CH;
  float* psV    = pmV + 2 * CH;
  float* atPrev = psV + 2 * CH;              // CH
  float* atF    = atPrev + CH;               // CH
  float* btF    = atF + CH;                  // CH
  float* errD   = btF + CH;                  // 16 floats
  int*   bars   = (int*)(errD + NB);         // 33 ints: barU[16], barV[16], root
  int*   barU   = bars;
  int*   barV   = bars + 16;
  int*   root   = bars + 32;

  prep_kernel<<<1024, 256, 0, stream>>>(x, y, xhp, xlp, yhp, ylp, nxs, nys, bars);
  sinkhorn_iterate<<<1024, 256, 0, stream>>>(xhp, xlp, yhp, ylp, nxs, nys,
                                             pmU, psU, pmV, psV,
                                             atPrev, errD, barU, barV, root);
  finalize_duals<<<64, 256, 0, stream>>>(pmU, psU, pmV, psV, atF, btF);
  pi_mfma<<<4096, 256, 0, stream>>>(xhp, xlp, yhp, ylp, atF, btF, pi);
}

// Round 15
// 2974.990 us; speedup vs baseline: 1.1480x; 1.1480x over previous
//
#include <hip/hip_runtime.h>
#include <math.h>

#define NB 16
#define PP 1024
#define DD 64
#define MAX_ITER 10
#define CH (NB * PP)           // partial-chunk stride (16384)
#define WPB 64                 // workgroups per batch
#define PADI 64                // ints per padded counter slot (256 B)

constexpr float EPSV    = 0.1f;
constexpr float SCALE_G = 20.0f;     // 2/eps
constexpr float LOG2E   = 1.44269504088896340736f;
constexpr float LOG_MU  = -6.93146156597137f;   // log(1/1024 + 1e-8)
constexpr float THRESHV = 0.1f;

typedef short bf16x8 __attribute__((ext_vector_type(8)));
typedef float f32x16 __attribute__((ext_vector_type(16)));

__device__ __forceinline__ unsigned short f2bf(float f) {
  unsigned int u = __float_as_uint(f);
  return (unsigned short)((u + 0x7FFFu + ((u >> 16) & 1u)) >> 16);   // RNE
}
__device__ __forceinline__ float bf2f(unsigned short h) {
  return __uint_as_float(((unsigned int)h) << 16);
}

// Packed-fragment addressing (validated r13): pk[((g*4+q)*64+lane)*8] = the
// bf16x8 lane needs for K-slice q of 32-row group g. Same layout for A and B.
__device__ __forceinline__ const bf16x8* frag(const unsigned short* pk, int g, int q, int l) {
  return (const bf16x8*)(pk + (((size_t)g * 4 + q) * 64 + l) * 8);
}

// ---------------------------------------------------------------------------
// Prep (validated r13): bf16 hi/lo split into packed fragments + norms.
// Block 0 zeroes all padded barrier slots (3200 ints, fresh every call).
// ---------------------------------------------------------------------------
__global__ __launch_bounds__(256) void prep_kernel(
    const float* __restrict__ x, const float* __restrict__ y,
    unsigned short* __restrict__ xhp, unsigned short* __restrict__ xlp,
    unsigned short* __restrict__ yhp, unsigned short* __restrict__ ylp,
    float* __restrict__ nxs, float* __restrict__ nys, int* __restrict__ bars)
{
  if (blockIdx.x == 0) {
    for (int t = threadIdx.x; t < (3 * NB + 2) * PADI; t += 256) bars[t] = 0;
  }

  const int sel = blockIdx.x >> 9;
  const int row = (blockIdx.x & 511) * 32 + (threadIdx.x >> 3);
  const int q   = threadIdx.x & 7;

  const float* src = sel ? y : x;
  unsigned short* H = sel ? yhp : xhp;
  unsigned short* L = sel ? ylp : xlp;
  float* N          = sel ? nys : nxs;

  const float* p = src + (size_t)row * DD + q * 8;
  float4 v0 = *(const float4*)(p);
  float4 v1 = *(const float4*)(p + 4);

  float f[8] = {v0.x, v0.y, v0.z, v0.w, v1.x, v1.y, v1.z, v1.w};
  float nrm = 0.f;
  unsigned short hb[8], lb[8];
  #pragma unroll
  for (int k = 0; k < 8; ++k) {
    nrm = fmaf(f[k], f[k], nrm);
    unsigned short h = f2bf(f[k]);
    float res = f[k] - bf2f(h);
    hb[k] = h; lb[k] = f2bf(res);
  }
  nrm += __shfl_xor(nrm, 1);
  nrm += __shfl_xor(nrm, 2);
  nrm += __shfl_xor(nrm, 4);
  if (q == 0) N[row] = 10.0f * nrm;

  uint4 ho, lo;
  ho.x = hb[0] | ((unsigned)hb[1] << 16); ho.y = hb[2] | ((unsigned)hb[3] << 16);
  ho.z = hb[4] | ((unsigned)hb[5] << 16); ho.w = hb[6] | ((unsigned)hb[7] << 16);
  lo.x = lb[0] | ((unsigned)lb[1] << 16); lo.y = lb[2] | ((unsigned)lb[3] << 16);
  lo.z = lb[4] | ((unsigned)lb[5] << 16); lo.w = lb[6] | ((unsigned)lb[7] << 16);

  const int grp  = row >> 5;
  const int lane = (row & 31) + 32 * (q & 1);
  const size_t dst = (((size_t)grp * 4 + (q >> 1)) * 64 + lane) * 8;
  *(uint4*)(H + dst) = ho;
  *(uint4*)(L + dst) = lo;
}

// ---------------------------------------------------------------------------
// Whole 10-iteration loop in one dispatch (phase bodies = validated r14).
// Sync: padded counters + tree-broadcast go-epochs, s_sleep backoff.
//   U done:  block-> barU[n] ; leader polls -> goU[n]=it+1 ; others poll goU.
//   iter end: block-> barV[n]; leaders -> root; block0 computes done from
//   errD and publishes globalGo = ((it+1)<<1)|done; everyone polls globalGo.
// All targets monotonic (no resets). Frozen blocks still arrive everywhere.
// ---------------------------------------------------------------------------
__global__ __launch_bounds__(256, 4) void sinkhorn_iterate(
    const unsigned short* __restrict__ xhp, const unsigned short* __restrict__ xlp,
    const unsigned short* __restrict__ yhp, const unsigned short* __restrict__ ylp,
    const float* __restrict__ nxs, const float* __restrict__ nys,
    float* __restrict__ pmU, float* __restrict__ psU,
    float* __restrict__ pmV, float* __restrict__ psV,
    float* __restrict__ atPrev, float* __restrict__ errD,
    int* __restrict__ barU, int* __restrict__ goU,
    int* __restrict__ barV, int* __restrict__ rootAndGo)
{
  const int tid = threadIdx.x;
  const int n     = blockIdx.x & 15;
  const int rem   = blockIdx.x >> 4;
  const int otile = rem >> 1;
  const int rc    = rem & 1;
  const int l     = tid & 63;
  const int w     = tid >> 6;

  int* root     = rootAndGo;
  int* globalGo = rootAndGo + PADI;

  __shared__ float bias[PP];
  __shared__ float mred[4][32];
  __shared__ float sred[4][32];
  __shared__ float red4[4];
  __shared__ int   sDone;

  if (tid == 0) sDone = 0;
  const int gB = n * 32 + otile;

  for (int it = 0; it < MAX_ITER; ++it) {
    __syncthreads();
    const int done = sDone;

    // ================= U phase (A=y reduce, B=x out) =================
    if (!done) {
      {
        const int e0 = tid * 4;
        if (it == 0) {
          float4 nv = *(const float4*)(nys + n * PP + e0);
          bias[e0+0] = -nv.x; bias[e0+1] = -nv.y; bias[e0+2] = -nv.z; bias[e0+3] = -nv.w;
        } else {
          float4 m0 = *(const float4*)(pmV + 0 * CH + n * PP + e0);
          float4 m1 = *(const float4*)(pmV + 1 * CH + n * PP + e0);
          float4 s0 = *(const float4*)(psV + 0 * CH + n * PP + e0);
          float4 s1 = *(const float4*)(psV + 1 * CH + n * PP + e0);
          float mm, ss;
          mm = fmaxf(m0.x, m1.x);
          ss = s0.x * exp2f((m0.x - mm) * LOG2E) + s1.x * exp2f((m1.x - mm) * LOG2E);
          bias[e0+0] = LOG_MU - (mm + logf(ss));
          mm = fmaxf(m0.y, m1.y);
          ss = s0.y * exp2f((m0.y - mm) * LOG2E) + s1.y * exp2f((m1.y - mm) * LOG2E);
          bias[e0+1] = LOG_MU - (mm + logf(ss));
          mm = fmaxf(m0.z, m1.z);
          ss = s0.z * exp2f((m0.z - mm) * LOG2E) + s1.z * exp2f((m1.z - mm) * LOG2E);
          bias[e0+2] = LOG_MU - (mm + logf(ss));
          mm = fmaxf(m0.w, m1.w);
          ss = s0.w * exp2f((m0.w - mm) * LOG2E) + s1.w * exp2f((m1.w - mm) * LOG2E);
          bias[e0+3] = LOG_MU - (mm + logf(ss));
        }
      }
      __syncthreads();

      bf16x8 Bh[4], Bl[4];
      #pragma unroll
      for (int q = 0; q < 4; ++q) {
        Bh[q] = *frag(xhp, gB, q, l);
        Bl[q] = *frag(xlp, gB, q, l);
      }

      float M = -INFINITY;
      #pragma unroll
      for (int jt = 0; jt < 4; ++jt) {
        const int gl = rc * 16 + w * 4 + jt;
        const int gA = n * 32 + gl;
        f32x16 a0;
        #pragma unroll
        for (int z = 0; z < 16; ++z) a0[z] = 0.f;
        #pragma unroll
        for (int q = 0; q < 4; ++q)
          a0 = __builtin_amdgcn_mfma_f32_32x32x16_bf16(*frag(yhp, gA, q, l), Bh[q], a0, 0, 0, 0);
        const int jb = gl * 32 + 4 * (l >> 5);
        #pragma unroll
        for (int r = 0; r < 16; ++r)
          M = fmaxf(M, fmaf(SCALE_G, a0[r], bias[jb + (r & 3) + 8 * (r >> 2)]));
      }
      M = fmaxf(M, __shfl_xor(M, 32));
      if (l < 32) mred[w][l] = M;
      __syncthreads();
      const int c = l & 31;
      const float Mf = fmaxf(fmaxf(mred[0][c], mred[1][c]), fmaxf(mred[2][c], mred[3][c]));

      float S = 0.f;
      #pragma unroll
      for (int jt = 0; jt < 4; ++jt) {
        const int gl = rc * 16 + w * 4 + jt;
        const int gA = n * 32 + gl;
        f32x16 a0, a1, a2;
        #pragma unroll
        for (int z = 0; z < 16; ++z) { a0[z] = 0.f; a1[z] = 0.f; a2[z] = 0.f; }
        #pragma unroll
        for (int q = 0; q < 4; ++q) {
          bf16x8 Ah = *frag(yhp, gA, q, l);
          bf16x8 Al = *frag(ylp, gA, q, l);
          a0 = __builtin_amdgcn_mfma_f32_32x32x16_bf16(Ah, Bh[q], a0, 0, 0, 0);
          a1 = __builtin_amdgcn_mfma_f32_32x32x16_bf16(Ah, Bl[q], a1, 0, 0, 0);
          a2 = __builtin_amdgcn_mfma_f32_32x32x16_bf16(Al, Bh[q], a2, 0, 0, 0);
        }
        const int jb = gl * 32 + 4 * (l >> 5);
        #pragma unroll
        for (int r = 0; r < 16; ++r)
          S += exp2f((fmaf(SCALE_G, a0[r] + a1[r] + a2[r], bias[jb + (r & 3) + 8 * (r >> 2)]) - Mf) * LOG2E);
      }
      S += __shfl_xor(S, 32);
      if (l < 32) sred[w][l] = S;
      __syncthreads();

      if (tid < 32) {
        float Sf = sred[0][tid] + sred[1][tid] + sred[2][tid] + sred[3][tid];
        float Mc = fmaxf(fmaxf(mred[0][tid], mred[1][tid]), fmaxf(mred[2][tid], mred[3][tid]));
        const int gi = n * PP + otile * 32 + tid;
        pmU[rc * CH + gi] = Mc;
        psU[rc * CH + gi] = Sf;
      }
    }

    // ---- batch barrier after U ----
    __syncthreads();
    if (tid == 0) {
      __threadfence();
      atomicAdd(&barU[n * PADI], 1);
      if (rem == 0) {
        while (__hip_atomic_load(&barU[n * PADI], __ATOMIC_RELAXED, __HIP_MEMORY_SCOPE_AGENT) < WPB * (it + 1))
          __builtin_amdgcn_s_sleep(16);
        __threadfence();
        __hip_atomic_store(&goU[n * PADI], it + 1, __ATOMIC_RELEASE, __HIP_MEMORY_SCOPE_AGENT);
      } else {
        while (__hip_atomic_load(&goU[n * PADI], __ATOMIC_ACQUIRE, __HIP_MEMORY_SCOPE_AGENT) < it + 1)
          __builtin_amdgcn_s_sleep(16);
      }
      __threadfence();
    }
    __syncthreads();

    // ================= V phase (A=x reduce, B=y out) =================
    if (!done) {
      float dsumT = 0.f;
      {
        const int e0 = tid * 4;
        float4 m0 = *(const float4*)(pmU + 0 * CH + n * PP + e0);
        float4 m1 = *(const float4*)(pmU + 1 * CH + n * PP + e0);
        float4 s0 = *(const float4*)(psU + 0 * CH + n * PP + e0);
        float4 s1 = *(const float4*)(psU + 1 * CH + n * PP + e0);
        float at4[4];
        float mm, ss;
        mm = fmaxf(m0.x, m1.x);
        ss = s0.x * exp2f((m0.x - mm) * LOG2E) + s1.x * exp2f((m1.x - mm) * LOG2E);
        at4[0] = LOG_MU - (mm + logf(ss));
        mm = fmaxf(m0.y, m1.y);
        ss = s0.y * exp2f((m0.y - mm) * LOG2E) + s1.y * exp2f((m1.y - mm) * LOG2E);
        at4[1] = LOG_MU - (mm + logf(ss));
        mm = fmaxf(m0.z, m1.z);
        ss = s0.z * exp2f((m0.z - mm) * LOG2E) + s1.z * exp2f((m1.z - mm) * LOG2E);
        at4[2] = LOG_MU - (mm + logf(ss));
        mm = fmaxf(m0.w, m1.w);
        ss = s0.w * exp2f((m0.w - mm) * LOG2E) + s1.w * exp2f((m1.w - mm) * LOG2E);
        at4[3] = LOG_MU - (mm + logf(ss));
        bias[e0+0] = at4[0]; bias[e0+1] = at4[1]; bias[e0+2] = at4[2]; bias[e0+3] = at4[3];
        if (rem == 0) {
          if (it == 0) {
            float4 nx = *(const float4*)(nxs + n * PP + e0);
            dsumT = fabsf(at4[0] + nx.x) + fabsf(at4[1] + nx.y)
                  + fabsf(at4[2] + nx.z) + fabsf(at4[3] + nx.w);
          } else {
            float4 ap = *(const float4*)(atPrev + n * PP + e0);
            dsumT = fabsf(at4[0] - ap.x) + fabsf(at4[1] - ap.y)
                  + fabsf(at4[2] - ap.z) + fabsf(at4[3] - ap.w);
          }
          *(float4*)(atPrev + n * PP + e0) = make_float4(at4[0], at4[1], at4[2], at4[3]);
        }
      }
      __syncthreads();

      bf16x8 Bh[4], Bl[4];
      #pragma unroll
      for (int q = 0; q < 4; ++q) {
        Bh[q] = *frag(yhp, gB, q, l);
        Bl[q] = *frag(ylp, gB, q, l);
      }

      float M = -INFINITY;
      #pragma unroll
      for (int jt = 0; jt < 4; ++jt) {
        const int gl = rc * 16 + w * 4 + jt;
        const int gA = n * 32 + gl;
        f32x16 a0;
        #pragma unroll
        for (int z = 0; z < 16; ++z) a0[z] = 0.f;
        #pragma unroll
        for (int q = 0; q < 4; ++q)
          a0 = __builtin_amdgcn_mfma_f32_32x32x16_bf16(*frag(xhp, gA, q, l), Bh[q], a0, 0, 0, 0);
        const int jb = gl * 32 + 4 * (l >> 5);
        #pragma unroll
        for (int r = 0; r < 16; ++r)
          M = fmaxf(M, fmaf(SCALE_G, a0[r], bias[jb + (r & 3) + 8 * (r >> 2)]));
      }
      M = fmaxf(M, __shfl_xor(M, 32));
      if (l < 32) mred[w][l] = M;
      __syncthreads();
      const int c = l & 31;
      const float Mf = fmaxf(fmaxf(mred[0][c], mred[1][c]), fmaxf(mred[2][c], mred[3][c]));

      float S = 0.f;
      #pragma unroll
      for (int jt = 0; jt < 4; ++jt) {
        const int gl = rc * 16 + w * 4 + jt;
        const int gA = n * 32 + gl;
        f32x16 a0, a1, a2;
        #pragma unroll
        for (int z = 0; z < 16; ++z) { a0[z] = 0.f; a1[z] = 0.f; a2[z] = 0.f; }
        #pragma unroll
        for (int q = 0; q < 4; ++q) {
          bf16x8 Ah = *frag(xhp, gA, q, l);
          bf16x8 Al = *frag(xlp, gA, q, l);
          a0 = __builtin_amdgcn_mfma_f32_32x32x16_bf16(Ah, Bh[q], a0, 0, 0, 0);
          a1 = __builtin_amdgcn_mfma_f32_32x32x16_bf16(Ah, Bl[q], a1, 0, 0, 0);
          a2 = __builtin_amdgcn_mfma_f32_32x32x16_bf16(Al, Bh[q], a2, 0, 0, 0);
        }
        const int jb = gl * 32 + 4 * (l >> 5);
        #pragma unroll
        for (int r = 0; r < 16; ++r)
          S += exp2f((fmaf(SCALE_G, a0[r] + a1[r] + a2[r], bias[jb + (r & 3) + 8 * (r >> 2)]) - Mf) * LOG2E);
      }
      S += __shfl_xor(S, 32);
      if (l < 32) sred[w][l] = S;
      __syncthreads();

      if (tid < 32) {
        float Sf = sred[0][tid] + sred[1][tid] + sred[2][tid] + sred[3][tid];
        float Mc = fmaxf(fmaxf(mred[0][tid], mred[1][tid]), fmaxf(mred[2][tid], mred[3][tid]));
        const int gi = n * PP + otile * 32 + tid;
        pmV[rc * CH + gi] = Mc;
        psV[rc * CH + gi] = Sf;
      }

      if (rem == 0) {
        #pragma unroll
        for (int off = 32; off; off >>= 1) dsumT += __shfl_xor(dsumT, off);
        if (l == 0) red4[w] = dsumT;
      }
      __syncthreads();
      if (rem == 0 && tid == 0)
        errD[n] = red4[0] + red4[1] + red4[2] + red4[3];
    }
    // frozen: errD untouched (stays below threshold) — matches reference freeze

    // ---- global barrier + done broadcast ----
    __syncthreads();
    if (tid == 0) {
      __threadfence();
      atomicAdd(&barV[n * PADI], 1);
      if (rem == 0) {
        while (__hip_atomic_load(&barV[n * PADI], __ATOMIC_RELAXED, __HIP_MEMORY_SCOPE_AGENT) < WPB * (it + 1))
          __builtin_amdgcn_s_sleep(16);
        __threadfence();
        atomicAdd(root, 1);
        if (n == 0) {   // block 0: root master
          while (__hip_atomic_load(root, __ATOMIC_RELAXED, __HIP_MEMORY_SCOPE_AGENT) < NB * (it + 1))
            __builtin_amdgcn_s_sleep(16);
          __threadfence();
          float tot = 0.f;
          #pragma unroll
          for (int k = 0; k < NB; ++k) tot += ((const volatile float*)errD)[k];
          const int dn = (tot * (EPSV / (float)NB) < THRESHV) ? 1 : 0;
          __hip_atomic_store(globalGo, ((it + 1) << 1) | dn, __ATOMIC_RELEASE, __HIP_MEMORY_SCOPE_AGENT);
        }
      }
      int gv;
      for (;;) {
        gv = __hip_atomic_load(globalGo, __ATOMIC_ACQUIRE, __HIP_MEMORY_SCOPE_AGENT);
        if ((gv >> 1) >= it + 1) break;
        __builtin_amdgcn_s_sleep(16);
      }
      __threadfence();
      sDone = gv & 1;
    }
    __syncthreads();
  }
}

// ---------------------------------------------------------------------------
// atF_i = LOG_MU - lse_U(i); btF_j = LOG_MU - lse_V(j). (validated r14)
// ---------------------------------------------------------------------------
__global__ __launch_bounds__(256) void finalize_duals(
    const float* __restrict__ pmU, const float* __restrict__ psU,
    const float* __restrict__ pmV, const float* __restrict__ psV,
    float* __restrict__ atF, float* __restrict__ btF)
{
  const int gi = blockIdx.x * 256 + threadIdx.x;
  float m0 = pmU[gi], m1 = pmU[CH + gi];
  float s0 = psU[gi], s1 = psU[CH + gi];
  float mm = fmaxf(m0, m1);
  float ss = s0 * exp2f((m0 - mm) * LOG2E) + s1 * exp2f((m1 - mm) * LOG2E);
  atF[gi] = LOG_MU - (mm + logf(ss));
  m0 = pmV[gi]; m1 = pmV[CH + gi];
  s0 = psV[gi]; s1 = psV[CH + gi];
  mm = fmaxf(m0, m1);
  ss = s0 * exp2f((m0 - mm) * LOG2E) + s1 * exp2f((m1 - mm) * LOG2E);
  btF[gi] = LOG_MU - (mm + logf(ss));
}

// ---------------------------------------------------------------------------
// pi_ij = exp(atF_i + btF_j + 20*<x_i,y_j>). (validated r14)
// ---------------------------------------------------------------------------
__global__ __launch_bounds__(256) void pi_mfma(
    const unsigned short* __restrict__ xhp, const unsigned short* __restrict__ xlp,
    const unsigned short* __restrict__ yhp, const unsigned short* __restrict__ ylp,
    const float* __restrict__ atF, const float* __restrict__ btF,
    float* __restrict__ pi)
{
  const int n   = blockIdx.x & 15;
  const int ib  = (blockIdx.x >> 4) & 15;
  const int jb  = blockIdx.x >> 8;
  const int tid = threadIdx.x;
  const int l   = tid & 63;
  const int w   = tid >> 6;
  const int ih  = w & 1, jh = w >> 1;

  __shared__ float atv[64];
  if (tid < 64) atv[tid] = atF[n * PP + ib * 64 + tid];
  __syncthreads();

  const int jg  = n * PP + jb * 64 + 32 * jh + (l & 31);
  const float btv = btF[jg];

  const int gX = n * 32 + ib * 2 + ih;
  const int gY = n * 32 + jb * 2 + jh;

  f32x16 acc;
  #pragma unroll
  for (int z = 0; z < 16; ++z) acc[z] = 0.f;
  #pragma unroll
  for (int q = 0; q < 4; ++q) {
    bf16x8 Xh = *frag(xhp, gX, q, l);
    bf16x8 Xl = *frag(xlp, gX, q, l);
    bf16x8 Yh = *frag(yhp, gY, q, l);
    bf16x8 Yl = *frag(ylp, gY, q, l);
    acc = __builtin_amdgcn_mfma_f32_32x32x16_bf16(Xh, Yh, acc, 0, 0, 0);
    acc = __builtin_amdgcn_mfma_f32_32x32x16_bf16(Xh, Yl, acc, 0, 0, 0);
    acc = __builtin_amdgcn_mfma_f32_32x32x16_bf16(Xl, Yh, acc, 0, 0, 0);
  }

  const int irb  = 32 * ih + 4 * (l >> 5);
  const int jcol = jb * 64 + 32 * jh + (l & 31);
  #pragma unroll
  for (int r = 0; r < 16; ++r) {
    const int irel = irb + (r & 3) + 8 * (r >> 2);
    const size_t off = ((size_t)(n * PP + ib * 64 + irel)) * PP + jcol;
    pi[off] = exp2f((atv[irel] + btv + SCALE_G * acc[r]) * LOG2E);
  }
}

extern "C" void kernel_launch(void* const* d_in, const int* in_sizes, int n_in,
                              void* d_out, int out_size, void* d_ws, size_t ws_size,
                              hipStream_t stream)
{
  const float* y = (const float*)d_in[0];   // setup_inputs order: y first
  const float* x = (const float*)d_in[1];
  float* pi = (float*)d_out;

  const size_t NE = (size_t)NB * PP * DD;
  unsigned short* xhp = (unsigned short*)d_ws;
  unsigned short* xlp = xhp + NE;
  unsigned short* yhp = xlp + NE;
  unsigned short* ylp = yhp + NE;
  float* nxs    = (float*)(ylp + NE);        // CH floats
  float* nys    = nxs + CH;                  // CH
  float* pmU    = nys + CH;                  // 2*CH
  float* psU    = pmU + 2 * CH;
  float* pmV    = psU + 2 * CH;
  float* psV    = pmV + 2 * CH;
  float* atPrev = psV + 2 * CH;              // CH
  float* atF    = atPrev + CH;               // CH
  float* btF    = atF + CH;                  // CH
  float* errD   = btF + CH;                  // NB floats
  int*   bars   = (int*)(errD + NB);         // (3*NB+2)*PADI ints, padded slots
  int*   barU   = bars;                      // NB slots
  int*   goU    = bars + NB * PADI;          // NB slots
  int*   barV   = bars + 2 * NB * PADI;      // NB slots
  int*   rootGo = bars + 3 * NB * PADI;      // root + globalGo (2 slots)

  prep_kernel<<<1024, 256, 0, stream>>>(x, y, xhp, xlp, yhp, ylp, nxs, nys, bars);
  sinkhorn_iterate<<<1024, 256, 0, stream>>>(xhp, xlp, yhp, ylp, nxs, nys,
                                             pmU, psU, pmV, psV,
                                             atPrev, errD, barU, goU, barV, rootGo);
  finalize_duals<<<64, 256, 0, stream>>>(pmU, psU, pmV, psV, atF, btF);
  pi_mfma<<<4096, 256, 0, stream>>>(xhp, xlp, yhp, ylp, atF, btF, pi);
}

// Round 16
// 366.679 us; speedup vs baseline: 9.3140x; 8.1133x over previous
//
#include <hip/hip_runtime.h>
#include <math.h>

#define NB 16
#define PP 1024
#define DD 64
#define MAX_ITER 10
#define RCH 16                 // rows per iter-block chunk
#define NCH (PP / RCH)         // 64 chunks per batch
#define NBLK (NB * NCH)        // 1024 iter blocks
#define CH (NB * PP)           // 16384

constexpr float EPSV    = 0.1f;
constexpr float SCALE_G = 20.0f;     // 2/eps
constexpr float LOG2E   = 1.44269504088896340736f;
constexpr float LOG_MU  = -6.93146156597137f;   // log(1/1024 + 1e-8)
constexpr float THRESHV = 0.1f;

typedef short bf16x8 __attribute__((ext_vector_type(8)));
typedef float f32x16 __attribute__((ext_vector_type(16)));

__device__ __forceinline__ unsigned short f2bf(float f) {
  unsigned int u = __float_as_uint(f);
  return (unsigned short)((u + 0x7FFFu + ((u >> 16) & 1u)) >> 16);   // RNE
}
__device__ __forceinline__ float bf2f(unsigned short h) {
  return __uint_as_float(((unsigned int)h) << 16);
}

// Packed-fragment addressing (validated r13): pk[((g*4+q)*64+lane)*8] = the
// bf16x8 lane needs for K-slice q of 32-row group g. Same layout for A and B.
__device__ __forceinline__ const bf16x8* frag(const unsigned short* pk, int g, int q, int l) {
  return (const bf16x8*)(pk + (((size_t)g * 4 + q) * 64 + l) * 8);
}

// ---------------------------------------------------------------------------
// Prep (validated r13): bf16 hi/lo split into packed fragments + norms.
// Idempotent — run twice (packed arrays are clobbered by pm/ps during iters).
// ---------------------------------------------------------------------------
__global__ __launch_bounds__(256) void prep_kernel(
    const float* __restrict__ x, const float* __restrict__ y,
    unsigned short* __restrict__ xhp, unsigned short* __restrict__ xlp,
    unsigned short* __restrict__ yhp, unsigned short* __restrict__ ylp,
    float* __restrict__ nxs, float* __restrict__ nys)
{
  const int sel = blockIdx.x >> 9;
  const int row = (blockIdx.x & 511) * 32 + (threadIdx.x >> 3);
  const int q   = threadIdx.x & 7;

  const float* src = sel ? y : x;
  unsigned short* H = sel ? yhp : xhp;
  unsigned short* L = sel ? ylp : xlp;
  float* N          = sel ? nys : nxs;

  const float* p = src + (size_t)row * DD + q * 8;
  float4 v0 = *(const float4*)(p);
  float4 v1 = *(const float4*)(p + 4);

  float f[8] = {v0.x, v0.y, v0.z, v0.w, v1.x, v1.y, v1.z, v1.w};
  float nrm = 0.f;
  unsigned short hb[8], lb[8];
  #pragma unroll
  for (int k = 0; k < 8; ++k) {
    nrm = fmaf(f[k], f[k], nrm);
    unsigned short h = f2bf(f[k]);
    float res = f[k] - bf2f(h);
    hb[k] = h; lb[k] = f2bf(res);
  }
  nrm += __shfl_xor(nrm, 1);
  nrm += __shfl_xor(nrm, 2);
  nrm += __shfl_xor(nrm, 4);
  if (q == 0) N[row] = 10.0f * nrm;

  uint4 ho, lo;
  ho.x = hb[0] | ((unsigned)hb[1] << 16); ho.y = hb[2] | ((unsigned)hb[3] << 16);
  ho.z = hb[4] | ((unsigned)hb[5] << 16); ho.w = hb[6] | ((unsigned)hb[7] << 16);
  lo.x = lb[0] | ((unsigned)lb[1] << 16); lo.y = lb[2] | ((unsigned)lb[3] << 16);
  lo.z = lb[4] | ((unsigned)lb[5] << 16); lo.w = lb[6] | ((unsigned)lb[7] << 16);

  const int grp  = row >> 5;
  const int lane = (row & 31) + 32 * (q & 1);
  const size_t dst = (((size_t)grp * 4 + (q >> 1)) * 64 + lane) * 8;
  *(uint4*)(H + dst) = ho;
  *(uint4*)(L + dst) = lo;
}

// ---------------------------------------------------------------------------
// Cs = nxs_i + nys_j - 20*<x_i,y_j> via split-bf16 MFMA, packed frags,
// XCD-aware decode (validated r13). Writes Cs to d_out.
// ---------------------------------------------------------------------------
__global__ __launch_bounds__(256) void compute_c_mfma(
    const unsigned short* __restrict__ xhp, const unsigned short* __restrict__ xlp,
    const float* __restrict__ nxs,
    const unsigned short* __restrict__ yhp, const unsigned short* __restrict__ ylp,
    const float* __restrict__ nys,
    float* __restrict__ Cs)
{
  const int n   = blockIdx.x & 15;
  const int ib  = (blockIdx.x >> 4) & 15;
  const int jb  = blockIdx.x >> 8;
  const int tid = threadIdx.x;
  const int l   = tid & 63;
  const int w   = tid >> 6;
  const int ih  = w & 1, jh = w >> 1;

  __shared__ float nxv[64];
  if (tid < 64) nxv[tid] = nxs[n * PP + ib * 64 + tid];
  __syncthreads();

  const int jg  = n * PP + jb * 64 + 32 * jh + (l & 31);
  const float nyv = nys[jg];

  const int gX = n * 32 + ib * 2 + ih;
  const int gY = n * 32 + jb * 2 + jh;

  f32x16 acc;
  #pragma unroll
  for (int z = 0; z < 16; ++z) acc[z] = 0.f;
  #pragma unroll
  for (int q = 0; q < 4; ++q) {
    bf16x8 Xh = *frag(xhp, gX, q, l);
    bf16x8 Xl = *frag(xlp, gX, q, l);
    bf16x8 Yh = *frag(yhp, gY, q, l);
    bf16x8 Yl = *frag(ylp, gY, q, l);
    acc = __builtin_amdgcn_mfma_f32_32x32x16_bf16(Xh, Yh, acc, 0, 0, 0);
    acc = __builtin_amdgcn_mfma_f32_32x32x16_bf16(Xh, Yl, acc, 0, 0, 0);
    acc = __builtin_amdgcn_mfma_f32_32x32x16_bf16(Xl, Yh, acc, 0, 0, 0);
  }

  const int irb  = 32 * ih + 4 * (l >> 5);
  const int jcol = jb * 64 + 32 * jh + (l & 31);
  #pragma unroll
  for (int r = 0; r < 16; ++r) {
    const int irel = irb + (r & 3) + 8 * (r >> 2);
    const size_t off = ((size_t)(n * PP + ib * 64 + irel)) * PP + jcol;
    Cs[off] = nxv[irel] + nyv - SCALE_G * acc[r];
  }
}

// ---------------------------------------------------------------------------
// Fused iteration (r6/r8 PROVEN, byte-identical): block = (n, rc) owns a
// 16x1024 chunk of Cs; row phase (u) two-pass in regs, col phase (v partials)
// two-pass from L1/L2. it==0: a_old=0, b=0.
// ---------------------------------------------------------------------------
__global__ __launch_bounds__(256, 4) void iter_fused(
    const float* __restrict__ Cs, float* __restrict__ aG, const float* __restrict__ bG,
    float* __restrict__ pm, float* __restrict__ ps, float* __restrict__ errBlk,
    const int* __restrict__ doneFlags, int it)
{
  if (it > 0 && doneFlags[it - 1]) return;   // frozen: a,b,partials untouched

  const int n   = blockIdx.x >> 6;
  const int rc  = blockIdx.x & (NCH - 1);
  const int tid = threadIdx.x;

  __shared__ float bb[PP];
  __shared__ float aArr[RCH];
  __shared__ float dsum[RCH];

  if (it == 0) {
    *(float4*)&bb[tid * 4] = make_float4(0.f, 0.f, 0.f, 0.f);
  } else {
    *(float4*)&bb[tid * 4] = *(const float4*)(bG + n * PP + tid * 4);
  }
  __syncthreads();

  // ---- row phase (two-pass in regs) ----
  const int r0  = tid >> 4;
  const int k   = tid & 15;
  const int row = n * PP + rc * RCH + r0;
  const float* crow = Cs + (size_t)row * PP + 4 * k;

  float4 tv[16];
  #pragma unroll
  for (int j = 0; j < 16; ++j) {
    float4 c4 = *(const float4*)(crow + 64 * j);
    float4 b4 = *(const float4*)&bb[4 * k + 64 * j];
    tv[j] = make_float4(b4.x - c4.x, b4.y - c4.y, b4.z - c4.z, b4.w - c4.w);
  }
  float m = -INFINITY;
  #pragma unroll
  for (int j = 0; j < 16; ++j)
    m = fmaxf(m, fmaxf(fmaxf(tv[j].x, tv[j].y), fmaxf(tv[j].z, tv[j].w)));
  #pragma unroll
  for (int mask = 8; mask; mask >>= 1) m = fmaxf(m, __shfl_xor(m, mask));

  float s = 0.f;
  #pragma unroll
  for (int j = 0; j < 16; ++j) {
    s += exp2f((tv[j].x - m) * LOG2E) + exp2f((tv[j].y - m) * LOG2E)
       + exp2f((tv[j].z - m) * LOG2E) + exp2f((tv[j].w - m) * LOG2E);
  }
  #pragma unroll
  for (int mask = 8; mask; mask >>= 1) s += __shfl_xor(s, mask);

  if (k == 0) {
    float aOld = (it == 0) ? 0.f : aG[row];
    float an = LOG_MU - (m + logf(s));
    aG[row]  = an;
    aArr[r0] = an;
    dsum[r0] = fabsf(an - aOld);
  }
  __syncthreads();
  if (tid == 0) {
    float e = 0.f;
    #pragma unroll
    for (int r = 0; r < RCH; ++r) e += dsum[r];
    errBlk[blockIdx.x] = e;
  }

  // ---- col phase (two-pass, chunk re-read from L1/L2) ----
  const int c0 = tid * 4;
  const float* cb = Cs + ((size_t)(n * PP + rc * RCH)) * PP + c0;

  float m0 = -INFINITY, m1 = -INFINITY, m2 = -INFINITY, m3 = -INFINITY;
  #pragma unroll
  for (int r = 0; r < RCH; ++r) {
    float ar = aArr[r];
    float4 c4 = *(const float4*)(cb + (size_t)r * PP);
    m0 = fmaxf(m0, ar - c4.x);
    m1 = fmaxf(m1, ar - c4.y);
    m2 = fmaxf(m2, ar - c4.z);
    m3 = fmaxf(m3, ar - c4.w);
  }
  float s0 = 0.f, s1 = 0.f, s2 = 0.f, s3 = 0.f;
  #pragma unroll
  for (int r = 0; r < RCH; ++r) {
    float ar = aArr[r];
    float4 c4 = *(const float4*)(cb + (size_t)r * PP);
    s0 += exp2f((ar - c4.x - m0) * LOG2E);
    s1 += exp2f((ar - c4.y - m1) * LOG2E);
    s2 += exp2f((ar - c4.z - m2) * LOG2E);
    s3 += exp2f((ar - c4.w - m3) * LOG2E);
  }
  size_t off = ((size_t)(n * NCH + rc)) * PP + c0;
  *(float4*)(pm + off) = make_float4(m0, m1, m2, m3);
  *(float4*)(ps + off) = make_float4(s0, s1, s2, s3);
}

// ---------------------------------------------------------------------------
// Combine partials -> b; block 0 reduces errBlk (fixed order) -> doneFlags[it].
// (r8 PROVEN, byte-identical)
// ---------------------------------------------------------------------------
__global__ __launch_bounds__(256) void v_combine(
    const float* __restrict__ pm, const float* __restrict__ ps,
    float* __restrict__ bG, const float* __restrict__ errBlk,
    int* __restrict__ doneFlags, int it)
{
  if (it > 0 && doneFlags[it - 1]) {
    if (blockIdx.x == 0 && threadIdx.x == 0) doneFlags[it] = 1;
    return;
  }
  const int col = blockIdx.x * 256 + threadIdx.x;   // 0..16383
  const int n = col >> 10, j = col & (PP - 1);
  const float* pmn = pm + (size_t)n * NCH * PP + j;
  const float* psn = ps + (size_t)n * NCH * PP + j;

  float m = -INFINITY, s = 0.f;
  #pragma unroll 8
  for (int c = 0; c < NCH; ++c) {
    float mc = pmn[(size_t)c * PP];
    float sc = psn[(size_t)c * PP];
    float mn = fmaxf(m, mc);
    s = fmaf(s, exp2f((m - mn) * LOG2E), sc * exp2f((mc - mn) * LOG2E));
    m = mn;
  }
  bG[col] = LOG_MU - (m + logf(s));

  if (blockIdx.x == 0) {
    __shared__ float red[4];
    float loc = 0.f;
    for (int t = threadIdx.x; t < NBLK; t += 256) loc += errBlk[t];
    #pragma unroll
    for (int off = 32; off > 0; off >>= 1) loc += __shfl_xor(loc, off);
    if ((threadIdx.x & 63) == 0) red[threadIdx.x >> 6] = loc;
    __syncthreads();
    if (threadIdx.x == 0) {
      float tot = red[0] + red[1] + red[2] + red[3];
      float err = tot * (EPSV / (float)NB);
      doneFlags[it] = (err < THRESHV) ? 1 : 0;
    }
  }
}

// ---------------------------------------------------------------------------
// pi_ij = exp((a_i - nxs_i) + (b_j - nys_j) + 20*<x_i,y_j>) — validated
// pi_mfma (r14/r15) with at/bt computed inline from aG,bG,nxs,nys.
// Writes d_out once; never reads it.
// ---------------------------------------------------------------------------
__global__ __launch_bounds__(256) void pi_mfma(
    const unsigned short* __restrict__ xhp, const unsigned short* __restrict__ xlp,
    const unsigned short* __restrict__ yhp, const unsigned short* __restrict__ ylp,
    const float* __restrict__ aG, const float* __restrict__ bG,
    const float* __restrict__ nxs, const float* __restrict__ nys,
    float* __restrict__ pi)
{
  const int n   = blockIdx.x & 15;
  const int ib  = (blockIdx.x >> 4) & 15;
  const int jb  = blockIdx.x >> 8;
  const int tid = threadIdx.x;
  const int l   = tid & 63;
  const int w   = tid >> 6;
  const int ih  = w & 1, jh = w >> 1;

  __shared__ float atv[64];
  if (tid < 64) {
    int gi = n * PP + ib * 64 + tid;
    atv[tid] = aG[gi] - nxs[gi];
  }
  __syncthreads();

  const int jg  = n * PP + jb * 64 + 32 * jh + (l & 31);
  const float btv = bG[jg] - nys[jg];

  const int gX = n * 32 + ib * 2 + ih;
  const int gY = n * 32 + jb * 2 + jh;

  f32x16 acc;
  #pragma unroll
  for (int z = 0; z < 16; ++z) acc[z] = 0.f;
  #pragma unroll
  for (int q = 0; q < 4; ++q) {
    bf16x8 Xh = *frag(xhp, gX, q, l);
    bf16x8 Xl = *frag(xlp, gX, q, l);
    bf16x8 Yh = *frag(yhp, gY, q, l);
    bf16x8 Yl = *frag(ylp, gY, q, l);
    acc = __builtin_amdgcn_mfma_f32_32x32x16_bf16(Xh, Yh, acc, 0, 0, 0);
    acc = __builtin_amdgcn_mfma_f32_32x32x16_bf16(Xh, Yl, acc, 0, 0, 0);
    acc = __builtin_amdgcn_mfma_f32_32x32x16_bf16(Xl, Yh, acc, 0, 0, 0);
  }

  const int irb  = 32 * ih + 4 * (l >> 5);
  const int jcol = jb * 64 + 32 * jh + (l & 31);
  #pragma unroll
  for (int r = 0; r < 16; ++r) {
    const int irel = irb + (r & 3) + 8 * (r >> 2);
    const size_t off = ((size_t)(n * PP + ib * 64 + irel)) * PP + jcol;
    pi[off] = exp2f((atv[irel] + btv + SCALE_G * acc[r]) * LOG2E);
  }
}

extern "C" void kernel_launch(void* const* d_in, const int* in_sizes, int n_in,
                              void* d_out, int out_size, void* d_ws, size_t ws_size,
                              hipStream_t stream)
{
  const float* y = (const float*)d_in[0];   // setup_inputs order: y first
  const float* x = (const float*)d_in[1];

  float* Cs = (float*)d_out;                 // Cs during iters; pi at the end

  // ws: first 8 MB is a UNION — packed bf16 frags (used by cc_mfma before the
  // loop and pi_mfma after a regenerating prep) alias pm/ps (used in the loop).
  const size_t NE = (size_t)NB * PP * DD;    // 1,048,576 elems per packed array
  unsigned short* xhp = (unsigned short*)d_ws;
  unsigned short* xlp = xhp + NE;
  unsigned short* yhp = xlp + NE;
  unsigned short* ylp = yhp + NE;
  float* pm = (float*)d_ws;                  // [NB][NCH][PP] = 4 MB
  float* ps = pm + (size_t)NB * NCH * PP;    // 4 MB

  float* tail   = (float*)((char*)d_ws + 4 * NE * sizeof(unsigned short)); // +8 MB
  float* nxs    = tail;                      // CH floats
  float* nys    = nxs + CH;                  // CH
  float* aG     = nys + CH;                  // CH
  float* bG     = aG + CH;                   // CH
  float* errBlk = bG + CH;                   // NBLK floats
  int*   doneFl = (int*)(errBlk + NBLK);     // MAX_ITER ints

  prep_kernel<<<1024, 256, 0, stream>>>(x, y, xhp, xlp, yhp, ylp, nxs, nys);
  compute_c_mfma<<<4096, 256, 0, stream>>>(xhp, xlp, nxs, yhp, ylp, nys, Cs);
  for (int it = 0; it < MAX_ITER; ++it) {
    iter_fused<<<NBLK, 256, 0, stream>>>(Cs, aG, bG, pm, ps, errBlk, doneFl, it);
    v_combine<<<NB * PP / 256, 256, 0, stream>>>(pm, ps, bG, errBlk, doneFl, it);
  }
  // regenerate packed frags (pm/ps clobbered them); idempotent
  prep_kernel<<<1024, 256, 0, stream>>>(x, y, xhp, xlp, yhp, ylp, nxs, nys);
  pi_mfma<<<4096, 256, 0, stream>>>(xhp, xlp, yhp, ylp, aG, bG, nxs, nys, Cs);
}

// Round 17
// 364.790 us; speedup vs baseline: 9.3622x; 1.0052x over previous
//
#include <hip/hip_runtime.h>
#include <math.h>

#define NB 16
#define PP 1024
#define DD 64
#define MAX_ITER 10
#define RCH 16                 // rows per iter-block chunk
#define NCH (PP / RCH)         // 64 chunks per batch
#define NBLK (NB * NCH)        // 1024 iter blocks
#define CH (NB * PP)           // 16384

constexpr float EPSV    = 0.1f;
constexpr float SCALE_G = 20.0f;     // 2/eps
constexpr float LOG2E   = 1.44269504088896340736f;
constexpr float LOG_MU  = -6.93146156597137f;   // log(1/1024 + 1e-8)
constexpr float THRESHV = 0.1f;

typedef short bf16x8 __attribute__((ext_vector_type(8)));
typedef float f32x16 __attribute__((ext_vector_type(16)));

__device__ __forceinline__ unsigned short f2bf(float f) {
  unsigned int u = __float_as_uint(f);
  return (unsigned short)((u + 0x7FFFu + ((u >> 16) & 1u)) >> 16);   // RNE
}
__device__ __forceinline__ float bf2f(unsigned short h) {
  return __uint_as_float(((unsigned int)h) << 16);
}

// Packed-fragment addressing (validated r13).
__device__ __forceinline__ const bf16x8* frag(const unsigned short* pk, int g, int q, int l) {
  return (const bf16x8*)(pk + (((size_t)g * 4 + q) * 64 + l) * 8);
}

// ---------------------------------------------------------------------------
// Prep (validated r13): bf16 hi/lo split into packed fragments + norms.
// Idempotent — run twice (packed arrays are clobbered by pm/ps during iters).
// ---------------------------------------------------------------------------
__global__ __launch_bounds__(256) void prep_kernel(
    const float* __restrict__ x, const float* __restrict__ y,
    unsigned short* __restrict__ xhp, unsigned short* __restrict__ xlp,
    unsigned short* __restrict__ yhp, unsigned short* __restrict__ ylp,
    float* __restrict__ nxs, float* __restrict__ nys)
{
  const int sel = blockIdx.x >> 9;
  const int row = (blockIdx.x & 511) * 32 + (threadIdx.x >> 3);
  const int q   = threadIdx.x & 7;

  const float* src = sel ? y : x;
  unsigned short* H = sel ? yhp : xhp;
  unsigned short* L = sel ? ylp : xlp;
  float* N          = sel ? nys : nxs;

  const float* p = src + (size_t)row * DD + q * 8;
  float4 v0 = *(const float4*)(p);
  float4 v1 = *(const float4*)(p + 4);

  float f[8] = {v0.x, v0.y, v0.z, v0.w, v1.x, v1.y, v1.z, v1.w};
  float nrm = 0.f;
  unsigned short hb[8], lb[8];
  #pragma unroll
  for (int k = 0; k < 8; ++k) {
    nrm = fmaf(f[k], f[k], nrm);
    unsigned short h = f2bf(f[k]);
    float res = f[k] - bf2f(h);
    hb[k] = h; lb[k] = f2bf(res);
  }
  nrm += __shfl_xor(nrm, 1);
  nrm += __shfl_xor(nrm, 2);
  nrm += __shfl_xor(nrm, 4);
  if (q == 0) N[row] = 10.0f * nrm;

  uint4 ho, lo;
  ho.x = hb[0] | ((unsigned)hb[1] << 16); ho.y = hb[2] | ((unsigned)hb[3] << 16);
  ho.z = hb[4] | ((unsigned)hb[5] << 16); ho.w = hb[6] | ((unsigned)hb[7] << 16);
  lo.x = lb[0] | ((unsigned)lb[1] << 16); lo.y = lb[2] | ((unsigned)lb[3] << 16);
  lo.z = lb[4] | ((unsigned)lb[5] << 16); lo.w = lb[6] | ((unsigned)lb[7] << 16);

  const int grp  = row >> 5;
  const int lane = (row & 31) + 32 * (q & 1);
  const size_t dst = (((size_t)grp * 4 + (q >> 1)) * 64 + lane) * 8;
  *(uint4*)(H + dst) = ho;
  *(uint4*)(L + dst) = lo;
}

// ---------------------------------------------------------------------------
// Cs = nxs_i + nys_j - 20*<x_i,y_j> via split-bf16 MFMA (validated r13/r16).
// ---------------------------------------------------------------------------
__global__ __launch_bounds__(256) void compute_c_mfma(
    const unsigned short* __restrict__ xhp, const unsigned short* __restrict__ xlp,
    const float* __restrict__ nxs,
    const unsigned short* __restrict__ yhp, const unsigned short* __restrict__ ylp,
    const float* __restrict__ nys,
    float* __restrict__ Cs)
{
  const int n   = blockIdx.x & 15;
  const int ib  = (blockIdx.x >> 4) & 15;
  const int jb  = blockIdx.x >> 8;
  const int tid = threadIdx.x;
  const int l   = tid & 63;
  const int w   = tid >> 6;
  const int ih  = w & 1, jh = w >> 1;

  __shared__ float nxv[64];
  if (tid < 64) nxv[tid] = nxs[n * PP + ib * 64 + tid];
  __syncthreads();

  const int jg  = n * PP + jb * 64 + 32 * jh + (l & 31);
  const float nyv = nys[jg];

  const int gX = n * 32 + ib * 2 + ih;
  const int gY = n * 32 + jb * 2 + jh;

  f32x16 acc;
  #pragma unroll
  for (int z = 0; z < 16; ++z) acc[z] = 0.f;
  #pragma unroll
  for (int q = 0; q < 4; ++q) {
    bf16x8 Xh = *frag(xhp, gX, q, l);
    bf16x8 Xl = *frag(xlp, gX, q, l);
    bf16x8 Yh = *frag(yhp, gY, q, l);
    bf16x8 Yl = *frag(ylp, gY, q, l);
    acc = __builtin_amdgcn_mfma_f32_32x32x16_bf16(Xh, Yh, acc, 0, 0, 0);
    acc = __builtin_amdgcn_mfma_f32_32x32x16_bf16(Xh, Yl, acc, 0, 0, 0);
    acc = __builtin_amdgcn_mfma_f32_32x32x16_bf16(Xl, Yh, acc, 0, 0, 0);
  }

  const int irb  = 32 * ih + 4 * (l >> 5);
  const int jcol = jb * 64 + 32 * jh + (l & 31);
  #pragma unroll
  for (int r = 0; r < 16; ++r) {
    const int irel = irb + (r & 3) + 8 * (r >> 2);
    const size_t off = ((size_t)(n * PP + ib * 64 + irel)) * PP + jcol;
    Cs[off] = nxv[irel] + nyv - SCALE_G * acc[r];
  }
}

// ---------------------------------------------------------------------------
// Fused iteration, ROW PHASE REWRITTEN for wave-contiguous streaming:
// wave w owns rows 4w..4w+3 of the block's 16-row chunk; each load instr
// covers 1 KB contiguous (64 lanes x float4); consecutive instrs walk memory
// sequentially. 4 parallel 64-lane butterflies for (m,s). Col phase and all
// plumbing byte-identical to r16 (PROVEN). Decode n=bid&15 (XCD-pin batches).
// ---------------------------------------------------------------------------
__global__ __launch_bounds__(256, 4) void iter_fused(
    const float* __restrict__ Cs, float* __restrict__ aG, const float* __restrict__ bG,
    float* __restrict__ pm, float* __restrict__ ps, float* __restrict__ errBlk,
    const int* __restrict__ doneFlags, int it)
{
  if (it > 0 && doneFlags[it - 1]) return;   // frozen: a,b,partials untouched

  const int n   = blockIdx.x & 15;
  const int rc  = blockIdx.x >> 4;
  const int tid = threadIdx.x;
  const int l   = tid & 63;
  const int wv  = tid >> 6;

  __shared__ float bb[PP];
  __shared__ float aArr[RCH];
  __shared__ float dsum[RCH];

  if (it == 0) {
    *(float4*)&bb[tid * 4] = make_float4(0.f, 0.f, 0.f, 0.f);
  } else {
    *(float4*)&bb[tid * 4] = *(const float4*)(bG + n * PP + tid * 4);
  }
  __syncthreads();

  // ---- row phase: wave w streams rows 4w..4w+3 (16 KB contiguous) ----
  const int rbase = rc * RCH + 4 * wv;            // first row of this wave
  const float* cbase = Cs + ((size_t)(n * PP + rbase)) * PP;

  float4 bbv[4];
  #pragma unroll
  for (int s = 0; s < 4; ++s) bbv[s] = *(const float4*)&bb[s * 256 + l * 4];

  float4 tv[16];
  #pragma unroll
  for (int t = 0; t < 16; ++t) {
    const int r = t >> 2, s = t & 3;
    float4 c4 = *(const float4*)(cbase + (size_t)r * PP + s * 256 + l * 4);
    tv[t] = make_float4(bbv[s].x - c4.x, bbv[s].y - c4.y,
                        bbv[s].z - c4.z, bbv[s].w - c4.w);
  }

  float m0 = -INFINITY, m1 = -INFINITY, m2 = -INFINITY, m3 = -INFINITY;
  #pragma unroll
  for (int s = 0; s < 4; ++s) {
    m0 = fmaxf(m0, fmaxf(fmaxf(tv[s].x, tv[s].y), fmaxf(tv[s].z, tv[s].w)));
    m1 = fmaxf(m1, fmaxf(fmaxf(tv[4+s].x, tv[4+s].y), fmaxf(tv[4+s].z, tv[4+s].w)));
    m2 = fmaxf(m2, fmaxf(fmaxf(tv[8+s].x, tv[8+s].y), fmaxf(tv[8+s].z, tv[8+s].w)));
    m3 = fmaxf(m3, fmaxf(fmaxf(tv[12+s].x, tv[12+s].y), fmaxf(tv[12+s].z, tv[12+s].w)));
  }
  #pragma unroll
  for (int mask = 32; mask; mask >>= 1) {
    m0 = fmaxf(m0, __shfl_xor(m0, mask));
    m1 = fmaxf(m1, __shfl_xor(m1, mask));
    m2 = fmaxf(m2, __shfl_xor(m2, mask));
    m3 = fmaxf(m3, __shfl_xor(m3, mask));
  }

  float s0 = 0.f, s1 = 0.f, s2 = 0.f, s3 = 0.f;
  #pragma unroll
  for (int s = 0; s < 4; ++s) {
    s0 += exp2f((tv[s].x - m0) * LOG2E) + exp2f((tv[s].y - m0) * LOG2E)
        + exp2f((tv[s].z - m0) * LOG2E) + exp2f((tv[s].w - m0) * LOG2E);
    s1 += exp2f((tv[4+s].x - m1) * LOG2E) + exp2f((tv[4+s].y - m1) * LOG2E)
        + exp2f((tv[4+s].z - m1) * LOG2E) + exp2f((tv[4+s].w - m1) * LOG2E);
    s2 += exp2f((tv[8+s].x - m2) * LOG2E) + exp2f((tv[8+s].y - m2) * LOG2E)
        + exp2f((tv[8+s].z - m2) * LOG2E) + exp2f((tv[8+s].w - m2) * LOG2E);
    s3 += exp2f((tv[12+s].x - m3) * LOG2E) + exp2f((tv[12+s].y - m3) * LOG2E)
        + exp2f((tv[12+s].z - m3) * LOG2E) + exp2f((tv[12+s].w - m3) * LOG2E);
  }
  #pragma unroll
  for (int mask = 32; mask; mask >>= 1) {
    s0 += __shfl_xor(s0, mask);
    s1 += __shfl_xor(s1, mask);
    s2 += __shfl_xor(s2, mask);
    s3 += __shfl_xor(s3, mask);
  }

  if (l == 0) {
    float mg[4] = {m0, m1, m2, m3};
    float sg[4] = {s0, s1, s2, s3};
    #pragma unroll
    for (int g = 0; g < 4; ++g) {
      const int row = n * PP + rbase + g;
      float aOld = (it == 0) ? 0.f : aG[row];
      float an = LOG_MU - (mg[g] + logf(sg[g]));
      aG[row] = an;
      aArr[4 * wv + g] = an;
      dsum[4 * wv + g] = fabsf(an - aOld);
    }
  }
  __syncthreads();
  if (tid == 0) {
    float e = 0.f;
    #pragma unroll
    for (int r = 0; r < RCH; ++r) e += dsum[r];
    errBlk[blockIdx.x] = e;
  }

  // ---- col phase (two-pass, chunk re-read from L1/L2) — r16 byte-identical ----
  const int c0 = tid * 4;
  const float* cb = Cs + ((size_t)(n * PP + rc * RCH)) * PP + c0;

  float cm0 = -INFINITY, cm1 = -INFINITY, cm2 = -INFINITY, cm3 = -INFINITY;
  #pragma unroll
  for (int r = 0; r < RCH; ++r) {
    float ar = aArr[r];
    float4 c4 = *(const float4*)(cb + (size_t)r * PP);
    cm0 = fmaxf(cm0, ar - c4.x);
    cm1 = fmaxf(cm1, ar - c4.y);
    cm2 = fmaxf(cm2, ar - c4.z);
    cm3 = fmaxf(cm3, ar - c4.w);
  }
  float cs0 = 0.f, cs1 = 0.f, cs2 = 0.f, cs3 = 0.f;
  #pragma unroll
  for (int r = 0; r < RCH; ++r) {
    float ar = aArr[r];
    float4 c4 = *(const float4*)(cb + (size_t)r * PP);
    cs0 += exp2f((ar - c4.x - cm0) * LOG2E);
    cs1 += exp2f((ar - c4.y - cm1) * LOG2E);
    cs2 += exp2f((ar - c4.z - cm2) * LOG2E);
    cs3 += exp2f((ar - c4.w - cm3) * LOG2E);
  }
  size_t off = ((size_t)(n * NCH + rc)) * PP + c0;
  *(float4*)(pm + off) = make_float4(cm0, cm1, cm2, cm3);
  *(float4*)(ps + off) = make_float4(cs0, cs1, cs2, cs3);
}

// ---------------------------------------------------------------------------
// Combine partials -> b; block 0 reduces errBlk -> doneFlags[it]. (r16 PROVEN)
// ---------------------------------------------------------------------------
__global__ __launch_bounds__(256) void v_combine(
    const float* __restrict__ pm, const float* __restrict__ ps,
    float* __restrict__ bG, const float* __restrict__ errBlk,
    int* __restrict__ doneFlags, int it)
{
  if (it > 0 && doneFlags[it - 1]) {
    if (blockIdx.x == 0 && threadIdx.x == 0) doneFlags[it] = 1;
    return;
  }
  const int col = blockIdx.x * 256 + threadIdx.x;   // 0..16383
  const int n = col >> 10, j = col & (PP - 1);
  const float* pmn = pm + (size_t)n * NCH * PP + j;
  const float* psn = ps + (size_t)n * NCH * PP + j;

  float m = -INFINITY, s = 0.f;
  #pragma unroll 8
  for (int c = 0; c < NCH; ++c) {
    float mc = pmn[(size_t)c * PP];
    float sc = psn[(size_t)c * PP];
    float mn = fmaxf(m, mc);
    s = fmaf(s, exp2f((m - mn) * LOG2E), sc * exp2f((mc - mn) * LOG2E));
    m = mn;
  }
  bG[col] = LOG_MU - (m + logf(s));

  if (blockIdx.x == 0) {
    __shared__ float red[4];
    float loc = 0.f;
    for (int t = threadIdx.x; t < NBLK; t += 256) loc += errBlk[t];
    #pragma unroll
    for (int off = 32; off > 0; off >>= 1) loc += __shfl_xor(loc, off);
    if ((threadIdx.x & 63) == 0) red[threadIdx.x >> 6] = loc;
    __syncthreads();
    if (threadIdx.x == 0) {
      float tot = red[0] + red[1] + red[2] + red[3];
      float err = tot * (EPSV / (float)NB);
      doneFlags[it] = (err < THRESHV) ? 1 : 0;
    }
  }
}

// ---------------------------------------------------------------------------
// pi_ij = exp((a_i - nxs_i) + (b_j - nys_j) + 20*<x_i,y_j>). (r16 PROVEN)
// ---------------------------------------------------------------------------
__global__ __launch_bounds__(256) void pi_mfma(
    const unsigned short* __restrict__ xhp, const unsigned short* __restrict__ xlp,
    const unsigned short* __restrict__ yhp, const unsigned short* __restrict__ ylp,
    const float* __restrict__ aG, const float* __restrict__ bG,
    const float* __restrict__ nxs, const float* __restrict__ nys,
    float* __restrict__ pi)
{
  const int n   = blockIdx.x & 15;
  const int ib  = (blockIdx.x >> 4) & 15;
  const int jb  = blockIdx.x >> 8;
  const int tid = threadIdx.x;
  const int l   = tid & 63;
  const int w   = tid >> 6;
  const int ih  = w & 1, jh = w >> 1;

  __shared__ float atv[64];
  if (tid < 64) {
    int gi = n * PP + ib * 64 + tid;
    atv[tid] = aG[gi] - nxs[gi];
  }
  __syncthreads();

  const int jg  = n * PP + jb * 64 + 32 * jh + (l & 31);
  const float btv = bG[jg] - nys[jg];

  const int gX = n * 32 + ib * 2 + ih;
  const int gY = n * 32 + jb * 2 + jh;

  f32x16 acc;
  #pragma unroll
  for (int z = 0; z < 16; ++z) acc[z] = 0.f;
  #pragma unroll
  for (int q = 0; q < 4; ++q) {
    bf16x8 Xh = *frag(xhp, gX, q, l);
    bf16x8 Xl = *frag(xlp, gX, q, l);
    bf16x8 Yh = *frag(yhp, gY, q, l);
    bf16x8 Yl = *frag(ylp, gY, q, l);
    acc = __builtin_amdgcn_mfma_f32_32x32x16_bf16(Xh, Yh, acc, 0, 0, 0);
    acc = __builtin_amdgcn_mfma_f32_32x32x16_bf16(Xh, Yl, acc, 0, 0, 0);
    acc = __builtin_amdgcn_mfma_f32_32x32x16_bf16(Xl, Yh, acc, 0, 0, 0);
  }

  const int irb  = 32 * ih + 4 * (l >> 5);
  const int jcol = jb * 64 + 32 * jh + (l & 31);
  #pragma unroll
  for (int r = 0; r < 16; ++r) {
    const int irel = irb + (r & 3) + 8 * (r >> 2);
    const size_t off = ((size_t)(n * PP + ib * 64 + irel)) * PP + jcol;
    pi[off] = exp2f((atv[irel] + btv + SCALE_G * acc[r]) * LOG2E);
  }
}

extern "C" void kernel_launch(void* const* d_in, const int* in_sizes, int n_in,
                              void* d_out, int out_size, void* d_ws, size_t ws_size,
                              hipStream_t stream)
{
  const float* y = (const float*)d_in[0];   // setup_inputs order: y first
  const float* x = (const float*)d_in[1];

  float* Cs = (float*)d_out;                 // Cs during iters; pi at the end

  // ws: first 8 MB is a UNION — packed bf16 frags alias pm/ps (r16 PROVEN).
  const size_t NE = (size_t)NB * PP * DD;
  unsigned short* xhp = (unsigned short*)d_ws;
  unsigned short* xlp = xhp + NE;
  unsigned short* yhp = xlp + NE;
  unsigned short* ylp = yhp + NE;
  float* pm = (float*)d_ws;                  // 4 MB
  float* ps = pm + (size_t)NB * NCH * PP;    // 4 MB

  float* tail   = (float*)((char*)d_ws + 4 * NE * sizeof(unsigned short)); // +8 MB
  float* nxs    = tail;
  float* nys    = nxs + CH;
  float* aG     = nys + CH;
  float* bG     = aG + CH;
  float* errBlk = bG + CH;
  int*   doneFl = (int*)(errBlk + NBLK);

  prep_kernel<<<1024, 256, 0, stream>>>(x, y, xhp, xlp, yhp, ylp, nxs, nys);
  compute_c_mfma<<<4096, 256, 0, stream>>>(xhp, xlp, nxs, yhp, ylp, nys, Cs);
  for (int it = 0; it < MAX_ITER; ++it) {
    iter_fused<<<NBLK, 256, 0, stream>>>(Cs, aG, bG, pm, ps, errBlk, doneFl, it);
    v_combine<<<NB * PP / 256, 256, 0, stream>>>(pm, ps, bG, errBlk, doneFl, it);
  }
  // regenerate packed frags (pm/ps clobbered them); idempotent
  prep_kernel<<<1024, 256, 0, stream>>>(x, y, xhp, xlp, yhp, ylp, nxs, nys);
  pi_mfma<<<4096, 256, 0, stream>>>(xhp, xlp, yhp, ylp, aG, bG, nxs, nys, Cs);
}